// Round 1
// baseline (336.324 us; speedup 1.0000x reference)
//
#include <hip/hip_runtime.h>

#define D_FEAT 128

// One edge per 32 lanes: lane j loads float4 j of the src row and dst row
// (32 * 16B = 512B = the whole 128-float row), partial dot, 5-step shuffle
// reduce within the 32-lane group, lane 0 stores.
__global__ __launch_bounds__(256) void edge_dot_kernel(
    const int2* __restrict__ edges,
    const float* __restrict__ feat,
    float* __restrict__ out,
    int n_edges)
{
    int tid  = blockIdx.x * blockDim.x + threadIdx.x;
    int edge = tid >> 5;
    int sub  = tid & 31;
    if (edge >= n_edges) return;

    int2 e = edges[edge];                       // wave-broadcast load
    const float4* srow = (const float4*)(feat + (long)e.x * D_FEAT);
    const float4* drow = (const float4*)(feat + (long)e.y * D_FEAT);

    float4 a = srow[sub];
    float4 b = drow[sub];
    float p = a.x * b.x + a.y * b.y + a.z * b.z + a.w * b.w;

    // Reduce across the 32 lanes of this edge (xor masks < 32 stay in-group).
    p += __shfl_xor(p, 16);
    p += __shfl_xor(p, 8);
    p += __shfl_xor(p, 4);
    p += __shfl_xor(p, 2);
    p += __shfl_xor(p, 1);

    if (sub == 0) out[edge] = p;
}

extern "C" void kernel_launch(void* const* d_in, const int* in_sizes, int n_in,
                              void* d_out, int out_size, void* d_ws, size_t ws_size,
                              hipStream_t stream) {
    const int2*  edges = (const int2*)d_in[0];   // (N_EDGES, 2) int32
    const float* feat  = (const float*)d_in[1];  // (N_NODES, 128) fp32
    float*       out   = (float*)d_out;          // (N_EDGES, 1) fp32

    int n_edges = in_sizes[0] / 2;
    long threads = (long)n_edges * 32;
    int block = 256;
    int grid = (int)((threads + block - 1) / block);
    edge_dot_kernel<<<grid, block, 0, stream>>>(edges, feat, out, n_edges);
}